// Round 6
// baseline (1045.155 us; speedup 1.0000x reference)
//
#include <hip/hip_runtime.h>
#include <math.h>

#define NB 46
#define NS 50
#define ND 768
#define GAMA 0.96875f
#define NM 2300   // NB*NS rows

typedef float v2f __attribute__((ext_vector_type(2)));

// ---------------- Kernel 1: QKV projections (+bias, +pe for Q,K) ----------
__global__ __launch_bounds__(256) void qkv_gemm(
    const float* __restrict__ text_emb, const float* __restrict__ emb,
    const float* __restrict__ Wq, const float* __restrict__ bq,
    const float* __restrict__ Wk, const float* __restrict__ bk,
    const float* __restrict__ Wv, const float* __restrict__ bv,
    float* __restrict__ Q, float* __restrict__ K, float* __restrict__ V)
{
    const int z = blockIdx.z;
    const float* X    = (z == 0) ? text_emb : emb;
    const float* W    = (z == 0) ? Wq : (z == 1) ? Wk : Wv;
    const float* bias = (z == 0) ? bq : (z == 1) ? bk : bv;
    float* out        = (z == 0) ? Q  : (z == 1) ? K  : V;

    __shared__ float Xs[16][68];
    __shared__ float Ws[16][68];

    const int tid = threadIdx.x;
    const int tx = tid & 15, ty = tid >> 4;
    const int m0 = blockIdx.x * 64, n0 = blockIdx.y * 64;

    const int lrow = tid >> 2;        // 0..63
    const int lk   = (tid & 3) * 4;   // 0,4,8,12

    float acc[4][4];
    #pragma unroll
    for (int i = 0; i < 4; i++)
        #pragma unroll
        for (int j = 0; j < 4; j++) acc[i][j] = 0.f;

    for (int k0 = 0; k0 < ND; k0 += 16) {
        float4 xv = make_float4(0.f, 0.f, 0.f, 0.f);
        const int xm = m0 + lrow;
        if (xm < NM) xv = *reinterpret_cast<const float4*>(&X[xm * ND + k0 + lk]);
        const float4 wv = *reinterpret_cast<const float4*>(&W[(n0 + lrow) * ND + k0 + lk]);
        Xs[lk + 0][lrow] = xv.x; Xs[lk + 1][lrow] = xv.y;
        Xs[lk + 2][lrow] = xv.z; Xs[lk + 3][lrow] = xv.w;
        Ws[lk + 0][lrow] = wv.x; Ws[lk + 1][lrow] = wv.y;
        Ws[lk + 2][lrow] = wv.z; Ws[lk + 3][lrow] = wv.w;
        __syncthreads();
        #pragma unroll
        for (int k = 0; k < 16; k++) {
            const float4 a  = *reinterpret_cast<const float4*>(&Xs[k][4 * ty]);
            const float4 b4 = *reinterpret_cast<const float4*>(&Ws[k][4 * tx]);
            const float av[4]  = {a.x,  a.y,  a.z,  a.w};
            const float bv4[4] = {b4.x, b4.y, b4.z, b4.w};
            #pragma unroll
            for (int i = 0; i < 4; i++)
                #pragma unroll
                for (int j = 0; j < 4; j++) acc[i][j] += av[i] * bv4[j];
        }
        __syncthreads();
    }

    const float C2 = -0.0239861701969175f; // -2*ln(10000)/768
    #pragma unroll
    for (int i = 0; i < 4; i++) {
        const int m = m0 + 4 * ty + i;
        if (m >= NM) continue;
        const int bpos = m / NS;  // pe indexed by BATCH position (faithful to source)
        #pragma unroll
        for (int j = 0; j < 4; j++) {
            const int n = n0 + 4 * tx + j;
            float v = acc[i][j] + bias[n];
            if (z < 2) {
                const int h = n >> 1;
                const float ang = (float)bpos * expf((float)h * C2);
                v += (n & 1) ? cosf(ang) : sinf(ang);
            }
            out[m * ND + n] = v;
        }
    }
}

// ---------------- Kernel 2: scores+softmax+ctx, and Ag = gamma*Q_trans -----
__global__ __launch_bounds__(64) void attn(
    const float* __restrict__ Q, const float* __restrict__ K,
    const float* __restrict__ V,
    const float* __restrict__ lin_w, const float* __restrict__ lin_b,
    float* __restrict__ Ag, float* __restrict__ ctx_out)
{
    const int bq = blockIdx.x;
    const int b = bq / NS, q = bq % NS;
    const int lane = threadIdx.x;

    const float* Qr = Q + (b * NS + q) * ND;
    float qv[12];
    #pragma unroll
    for (int m = 0; m < 12; m++) qv[m] = Qr[m * 64 + lane];

    // scores: lane k ends up holding score[k]*8
    float mysc = 0.f;
    for (int k = 0; k < NS; k++) {
        const float* Kr = K + (b * NS + k) * ND;
        float s = 0.f;
        #pragma unroll
        for (int m = 0; m < 12; m++) s += qv[m] * Kr[m * 64 + lane];
        #pragma unroll
        for (int off = 32; off; off >>= 1) s += __shfl_xor(s, off);
        if (lane == k) mysc = s * 8.f;
    }
    // Q_trans row q: lane j holds Qt[j]; write Ag = gamma*(Qt + lin_b)
    float myqt = 0.f;
    for (int j = 0; j < NS; j++) {
        const float* Lr = lin_w + j * ND;
        float s = 0.f;
        #pragma unroll
        for (int m = 0; m < 12; m++) s += qv[m] * Lr[m * 64 + lane];
        #pragma unroll
        for (int off = 32; off; off >>= 1) s += __shfl_xor(s, off);
        if (lane == j) myqt = s;
    }
    if (lane < NS)
        Ag[b * (NS * NS) + q * NS + lane] = GAMA * (myqt + lin_b[lane]);

    // softmax over lanes 0..49
    const float sc = (lane < NS) ? mysc : -INFINITY;
    float mx = sc;
    #pragma unroll
    for (int off = 32; off; off >>= 1) mx = fmaxf(mx, __shfl_xor(mx, off));
    const float e = (lane < NS) ? expf(sc - mx) : 0.f;
    float sum = e;
    #pragma unroll
    for (int off = 32; off; off >>= 1) sum += __shfl_xor(sum, off);
    const float p = e / sum;

    // ctx row = sum_k p_k * V[b,k,:]
    float acc[12];
    #pragma unroll
    for (int m = 0; m < 12; m++) acc[m] = 0.f;
    for (int k = 0; k < NS; k++) {
        const float pk = __shfl(p, k);
        const float* Vr = V + (b * NS + k) * ND;
        #pragma unroll
        for (int m = 0; m < 12; m++) acc[m] += pk * Vr[m * 64 + lane];
    }
    float* Cr = ctx_out + (b * NS + q) * ND;
    #pragma unroll
    for (int m = 0; m < 12; m++) Cr[m * 64 + lane] = acc[m];
}

// ---------------- Kernel 3: gamma-decay recurrence --------------------------
// rec[i,b,:,:] = Ag_b @ rec[i-1,b,:,:] + ctx[i].
// Block = (b, 64-col chunk), 2 waves; wave w computes rows w*25..w*25+24.
// State round-trips through double-buffered LDS. A in LDS, read as broadcast
// ds_read_b128 (no s_load — R2 lesson). Per-wave live regs ~130 (R4 lesson).
// R6 change: __syncthreads() drains vmcnt(0) (ALL NT stores to HBM) every
// step — replaced with lgkmcnt(0)+raw s_barrier (LDS visibility is the only
// intra-step requirement; global stores retire in the shadow of compute and
// are drained once at kernel end). ctx loads issued at step start, BEFORE
// any store, so their vmcnt waits never force store retirement.
#define RPW 25
__global__ __launch_bounds__(128) void recur(
    const float* __restrict__ Ag, const float* __restrict__ ctx,
    float* __restrict__ rec)
{
    const int blk   = blockIdx.x;
    const int b     = blk / 12;
    const int chunk = blk - b * 12;
    const int tid   = threadIdx.x;
    const int lane  = tid & 63;
    const int wid   = tid >> 6;            // 0,1
    const int d     = chunk * 64 + lane;
    const int r0    = wid * RPW;           // 0,25

    __shared__ float Als[NS * 52];         // A rows padded 50->52 (16B-aligned)
    __shared__ float st[2][NS * 64];       // double-buffered state

    const float* __restrict__ Ab = Ag + b * (NS * NS);
    for (int idx = tid; idx < NS * NS; idx += 128) {
        const int r = idx / NS, j = idx - r * NS;
        Als[r * 52 + j] = Ab[idx];
    }

    // ---- step 0: s_0 = ctx[0] (each wave its 25 rows) ----
    #pragma unroll
    for (int k = 0; k < RPW; k++) {
        const int r = r0 + k;
        const float v = ctx[r * ND + d];
        st[0][r * 64 + lane] = v;
        __builtin_nontemporal_store(v, &rec[(b * NS + r) * ND + d]);
    }
    // LDS-only barrier (covers A staging + st[0] writes); no vmcnt drain
    asm volatile("s_waitcnt lgkmcnt(0)" ::: "memory");
    __builtin_amdgcn_s_barrier();
    asm volatile("" ::: "memory");

    int p = 0;
    for (int i = 1; i < NB; ++i) {
        const float* __restrict__ ctxi = ctx + i * NS * ND + d;
        float* __restrict__ reci = rec + (size_t)(i * NB + b) * NS * ND + d;

        // ALL ctx loads for this step, issued before any store of this step
        float cv[RPW];
        #pragma unroll
        for (int k = 0; k < RPW; k++) cv[k] = ctxi[(r0 + k) * ND];

        // full old state -> registers as pairs (ds_read2_b32-mergeable)
        v2f s2[25];
        #pragma unroll
        for (int j = 0; j < 25; j++) {
            s2[j].x = st[p][(2 * j)     * 64 + lane];
            s2[j].y = st[p][(2 * j + 1) * 64 + lane];
        }

        #pragma unroll
        for (int k = 0; k < RPW; k++) {
            const int r = r0 + k;
            const float* __restrict__ Ar = &Als[r * 52];
            v2f acc01; acc01.x = 0.f; acc01.y = 0.f;   // chains j%4==0 / 1
            v2f acc23; acc23.x = 0.f; acc23.y = 0.f;   // chains j%4==2 / 3
            #pragma unroll
            for (int jj = 0; jj < 48; jj += 4) {
                const float4 a4 = *reinterpret_cast<const float4*>(Ar + jj);
                v2f a01; a01.x = a4.x; a01.y = a4.y;
                v2f a23; a23.x = a4.z; a23.y = a4.w;
                acc01 += a01 * s2[jj / 2];
                acc23 += a23 * s2[jj / 2 + 1];
            }
            {   // j = 48,49 (pad lanes unused)
                const float4 a4 = *reinterpret_cast<const float4*>(Ar + 48);
                v2f a01; a01.x = a4.x; a01.y = a4.y;
                acc01 += a01 * s2[24];
            }
            // ((s0+s2)+(s1+s3)) + cv — identical order to R2..R5
            const float v = ((acc01.x + acc23.x) + (acc01.y + acc23.y)) + cv[k];
            st[p ^ 1][r * 64 + lane] = v;
            __builtin_nontemporal_store(v, &reci[r * ND]);
        }
        // LDS-only barrier: new state visible; stores keep floating
        asm volatile("s_waitcnt lgkmcnt(0)" ::: "memory");
        __builtin_amdgcn_s_barrier();
        asm volatile("" ::: "memory");
        p ^= 1;
    }
}

extern "C" void kernel_launch(void* const* d_in, const int* in_sizes, int n_in,
                              void* d_out, int out_size, void* d_ws, size_t ws_size,
                              hipStream_t stream) {
    const float* text_emb = (const float*)d_in[0];
    const float* emb      = (const float*)d_in[1];
    const float* Wq = (const float*)d_in[2]; const float* bq = (const float*)d_in[3];
    const float* Wk = (const float*)d_in[4]; const float* bk = (const float*)d_in[5];
    const float* Wv = (const float*)d_in[6]; const float* bv = (const float*)d_in[7];
    const float* lw = (const float*)d_in[8]; const float* lb = (const float*)d_in[9];

    float* out = (float*)d_out;
    float* ctx = out;                          // [46,50,768]
    float* rec = out + NB * NS * ND;           // [46,46,50,768]

    float* ws = (float*)d_ws;                  // needs 21.7 MB
    float* Q  = ws;
    float* K  = Q + NB * NS * ND;
    float* V  = K + NB * NS * ND;
    float* Ag = V + NB * NS * ND;              // gamma * Q_trans, [46,50,50]

    qkv_gemm<<<dim3(36, 12, 3), 256, 0, stream>>>(text_emb, emb, Wq, bq, Wk, bk, Wv, bv, Q, K, V);
    attn<<<dim3(NM), 64, 0, stream>>>(Q, K, V, lw, lb, Ag, ctx);
    recur<<<dim3(552), 128, 0, stream>>>(Ag, ctx, rec);
}

// Round 7
// 494.448 us; speedup vs baseline: 2.1138x; 2.1138x over previous
//
#include <hip/hip_runtime.h>
#include <math.h>

#define NB 46
#define NS 50
#define ND 768
#define GAMA 0.96875f
#define NM 2300   // NB*NS rows

typedef float v2f __attribute__((ext_vector_type(2)));

// ---------------- Kernel 1: QKV projections (+bias, +pe for Q,K) ----------
__global__ __launch_bounds__(256) void qkv_gemm(
    const float* __restrict__ text_emb, const float* __restrict__ emb,
    const float* __restrict__ Wq, const float* __restrict__ bq,
    const float* __restrict__ Wk, const float* __restrict__ bk,
    const float* __restrict__ Wv, const float* __restrict__ bv,
    float* __restrict__ Q, float* __restrict__ K, float* __restrict__ V)
{
    const int z = blockIdx.z;
    const float* X    = (z == 0) ? text_emb : emb;
    const float* W    = (z == 0) ? Wq : (z == 1) ? Wk : Wv;
    const float* bias = (z == 0) ? bq : (z == 1) ? bk : bv;
    float* out        = (z == 0) ? Q  : (z == 1) ? K  : V;

    __shared__ float Xs[16][68];
    __shared__ float Ws[16][68];

    const int tid = threadIdx.x;
    const int tx = tid & 15, ty = tid >> 4;
    const int m0 = blockIdx.x * 64, n0 = blockIdx.y * 64;

    const int lrow = tid >> 2;        // 0..63
    const int lk   = (tid & 3) * 4;   // 0,4,8,12

    float acc[4][4];
    #pragma unroll
    for (int i = 0; i < 4; i++)
        #pragma unroll
        for (int j = 0; j < 4; j++) acc[i][j] = 0.f;

    for (int k0 = 0; k0 < ND; k0 += 16) {
        float4 xv = make_float4(0.f, 0.f, 0.f, 0.f);
        const int xm = m0 + lrow;
        if (xm < NM) xv = *reinterpret_cast<const float4*>(&X[xm * ND + k0 + lk]);
        const float4 wv = *reinterpret_cast<const float4*>(&W[(n0 + lrow) * ND + k0 + lk]);
        Xs[lk + 0][lrow] = xv.x; Xs[lk + 1][lrow] = xv.y;
        Xs[lk + 2][lrow] = xv.z; Xs[lk + 3][lrow] = xv.w;
        Ws[lk + 0][lrow] = wv.x; Ws[lk + 1][lrow] = wv.y;
        Ws[lk + 2][lrow] = wv.z; Ws[lk + 3][lrow] = wv.w;
        __syncthreads();
        #pragma unroll
        for (int k = 0; k < 16; k++) {
            const float4 a  = *reinterpret_cast<const float4*>(&Xs[k][4 * ty]);
            const float4 b4 = *reinterpret_cast<const float4*>(&Ws[k][4 * tx]);
            const float av[4]  = {a.x,  a.y,  a.z,  a.w};
            const float bv4[4] = {b4.x, b4.y, b4.z, b4.w};
            #pragma unroll
            for (int i = 0; i < 4; i++)
                #pragma unroll
                for (int j = 0; j < 4; j++) acc[i][j] += av[i] * bv4[j];
        }
        __syncthreads();
    }

    const float C2 = -0.0239861701969175f; // -2*ln(10000)/768
    #pragma unroll
    for (int i = 0; i < 4; i++) {
        const int m = m0 + 4 * ty + i;
        if (m >= NM) continue;
        const int bpos = m / NS;  // pe indexed by BATCH position (faithful to source)
        #pragma unroll
        for (int j = 0; j < 4; j++) {
            const int n = n0 + 4 * tx + j;
            float v = acc[i][j] + bias[n];
            if (z < 2) {
                const int h = n >> 1;
                const float ang = (float)bpos * expf((float)h * C2);
                v += (n & 1) ? cosf(ang) : sinf(ang);
            }
            out[m * ND + n] = v;
        }
    }
}

// ---------------- Kernel 2: scores+softmax+ctx, and Ag = gamma*Q_trans -----
__global__ __launch_bounds__(64) void attn(
    const float* __restrict__ Q, const float* __restrict__ K,
    const float* __restrict__ V,
    const float* __restrict__ lin_w, const float* __restrict__ lin_b,
    float* __restrict__ Ag, float* __restrict__ ctx_out)
{
    const int bq = blockIdx.x;
    const int b = bq / NS, q = bq % NS;
    const int lane = threadIdx.x;

    const float* Qr = Q + (b * NS + q) * ND;
    float qv[12];
    #pragma unroll
    for (int m = 0; m < 12; m++) qv[m] = Qr[m * 64 + lane];

    // scores: lane k ends up holding score[k]*8
    float mysc = 0.f;
    for (int k = 0; k < NS; k++) {
        const float* Kr = K + (b * NS + k) * ND;
        float s = 0.f;
        #pragma unroll
        for (int m = 0; m < 12; m++) s += qv[m] * Kr[m * 64 + lane];
        #pragma unroll
        for (int off = 32; off; off >>= 1) s += __shfl_xor(s, off);
        if (lane == k) mysc = s * 8.f;
    }
    // Q_trans row q: lane j holds Qt[j]; write Ag = gamma*(Qt + lin_b)
    float myqt = 0.f;
    for (int j = 0; j < NS; j++) {
        const float* Lr = lin_w + j * ND;
        float s = 0.f;
        #pragma unroll
        for (int m = 0; m < 12; m++) s += qv[m] * Lr[m * 64 + lane];
        #pragma unroll
        for (int off = 32; off; off >>= 1) s += __shfl_xor(s, off);
        if (lane == j) myqt = s;
    }
    if (lane < NS)
        Ag[b * (NS * NS) + q * NS + lane] = GAMA * (myqt + lin_b[lane]);

    // softmax over lanes 0..49
    const float sc = (lane < NS) ? mysc : -INFINITY;
    float mx = sc;
    #pragma unroll
    for (int off = 32; off; off >>= 1) mx = fmaxf(mx, __shfl_xor(mx, off));
    const float e = (lane < NS) ? expf(sc - mx) : 0.f;
    float sum = e;
    #pragma unroll
    for (int off = 32; off; off >>= 1) sum += __shfl_xor(sum, off);
    const float p = e / sum;

    // ctx row = sum_k p_k * V[b,k,:]
    float acc[12];
    #pragma unroll
    for (int m = 0; m < 12; m++) acc[m] = 0.f;
    for (int k = 0; k < NS; k++) {
        const float pk = __shfl(p, k);
        const float* Vr = V + (b * NS + k) * ND;
        #pragma unroll
        for (int m = 0; m < 12; m++) acc[m] += pk * Vr[m * 64 + lane];
    }
    float* Cr = ctx_out + (b * NS + q) * ND;
    #pragma unroll
    for (int m = 0; m < 12; m++) Cr[m * 64 + lane] = acc[m];
}

// ---------------- Kernel 3: gamma-decay recurrence --------------------------
// rec[i,b,:,:] = Ag_b @ rec[i-1,b,:,:] + ctx[i].
// Block = (b, 64-col chunk), 4 waves; wave w computes rows w*13..min(w*13+12,49).
// State round-trips through double-buffered LDS. A in LDS, broadcast
// ds_read_b128 (no s_load — R2 lesson). ~120 live VGPRs (R4 lesson).
// R6 lesson (vmcnt FIFO): each step's ctx must be loaded BEFORE the previous
// step's NT stores enter the queue, i.e. prefetch distance = 1 step (R2's
// pattern) combined with LDS-only barriers (R6's pattern). Then no wait ever
// sits behind a young store, and stores retire in the shadow of compute.
// 4 waves (vs R5's 2) double waves/SIMD to ~2.2 for latency overlap.
#define RPW 13
__global__ __launch_bounds__(256) void recur(
    const float* __restrict__ Ag, const float* __restrict__ ctx,
    float* __restrict__ rec)
{
    const int blk   = blockIdx.x;
    const int b     = blk / 12;
    const int chunk = blk - b * 12;
    const int tid   = threadIdx.x;
    const int lane  = tid & 63;
    const int wid   = tid >> 6;            // 0..3
    const int d     = chunk * 64 + lane;
    const int r0    = wid * RPW;           // 0,13,26,39

    __shared__ float Als[NS * 52];         // A rows padded 50->52 (16B-aligned)
    __shared__ float st[2][NS * 64];       // double-buffered state

    const float* __restrict__ Ab = Ag + b * (NS * NS);
    for (int idx = tid; idx < NS * NS; idx += 256) {
        const int r = idx / NS, j = idx - r * NS;
        Als[r * 52 + j] = Ab[idx];
    }

    float cv[RPW], cvN[RPW];

    // ---- step 0: s_0 = ctx[0]; prefetch step 1 before any store ----
    #pragma unroll
    for (int k = 0; k < RPW; k++) {
        const int r = r0 + k;
        cv[k] = (r < NS) ? ctx[r * ND + d] : 0.f;
    }
    #pragma unroll
    for (int k = 0; k < RPW; k++) {
        const int r = r0 + k;
        cvN[k] = (r < NS) ? ctx[(NS + r) * ND + d] : 0.f;
    }
    #pragma unroll
    for (int k = 0; k < RPW; k++) {
        const int r = r0 + k;
        if (r < NS) {
            st[0][r * 64 + lane] = cv[k];
            __builtin_nontemporal_store(cv[k], &rec[(b * NS + r) * ND + d]);
        }
    }
    // LDS-only barrier (covers A staging + st[0] writes); no vmcnt drain
    asm volatile("s_waitcnt lgkmcnt(0)" ::: "memory");
    __builtin_amdgcn_s_barrier();
    asm volatile("" ::: "memory");

    int p = 0;
    for (int i = 1; i < NB; ++i) {
        // rotate; issue step-(i+1) loads BEFORE this step's stores (FIFO order!)
        #pragma unroll
        for (int k = 0; k < RPW; k++) cv[k] = cvN[k];
        if (i + 1 < NB) {
            const float* __restrict__ ctxn = ctx + (i + 1) * NS * ND + d;
            #pragma unroll
            for (int k = 0; k < RPW; k++) {
                const int r = r0 + k;
                if (r < NS) cvN[k] = ctxn[r * ND];
            }
        }

        // full old state -> registers as pairs (ds_read2_b32-mergeable)
        v2f s2[25];
        #pragma unroll
        for (int j = 0; j < 25; j++) {
            s2[j].x = st[p][(2 * j)     * 64 + lane];
            s2[j].y = st[p][(2 * j + 1) * 64 + lane];
        }

        float* __restrict__ reci = rec + (size_t)(i * NB + b) * NS * ND + d;

        #pragma unroll
        for (int k = 0; k < RPW; k++) {
            const int r = r0 + k;
            if (r < NS) {
                const float* __restrict__ Ar = &Als[r * 52];
                v2f acc01; acc01.x = 0.f; acc01.y = 0.f;   // chains j%4==0 / 1
                v2f acc23; acc23.x = 0.f; acc23.y = 0.f;   // chains j%4==2 / 3
                #pragma unroll
                for (int jj = 0; jj < 48; jj += 4) {
                    const float4 a4 = *reinterpret_cast<const float4*>(Ar + jj);
                    v2f a01; a01.x = a4.x; a01.y = a4.y;
                    v2f a23; a23.x = a4.z; a23.y = a4.w;
                    acc01 += a01 * s2[jj / 2];
                    acc23 += a23 * s2[jj / 2 + 1];
                }
                {   // j = 48,49 (pad lanes unused)
                    const float4 a4 = *reinterpret_cast<const float4*>(Ar + 48);
                    v2f a01; a01.x = a4.x; a01.y = a4.y;
                    acc01 += a01 * s2[24];
                }
                // ((s0+s2)+(s1+s3)) + cv — identical order to R2..R6
                const float v = ((acc01.x + acc23.x) + (acc01.y + acc23.y)) + cv[k];
                st[p ^ 1][r * 64 + lane] = v;
                __builtin_nontemporal_store(v, &reci[r * ND]);
            }
        }
        // LDS-only barrier: new state visible; stores keep floating
        asm volatile("s_waitcnt lgkmcnt(0)" ::: "memory");
        __builtin_amdgcn_s_barrier();
        asm volatile("" ::: "memory");
        p ^= 1;
    }
}

extern "C" void kernel_launch(void* const* d_in, const int* in_sizes, int n_in,
                              void* d_out, int out_size, void* d_ws, size_t ws_size,
                              hipStream_t stream) {
    const float* text_emb = (const float*)d_in[0];
    const float* emb      = (const float*)d_in[1];
    const float* Wq = (const float*)d_in[2]; const float* bq = (const float*)d_in[3];
    const float* Wk = (const float*)d_in[4]; const float* bk = (const float*)d_in[5];
    const float* Wv = (const float*)d_in[6]; const float* bv = (const float*)d_in[7];
    const float* lw = (const float*)d_in[8]; const float* lb = (const float*)d_in[9];

    float* out = (float*)d_out;
    float* ctx = out;                          // [46,50,768]
    float* rec = out + NB * NS * ND;           // [46,46,50,768]

    float* ws = (float*)d_ws;                  // needs 21.7 MB
    float* Q  = ws;
    float* K  = Q + NB * NS * ND;
    float* V  = K + NB * NS * ND;
    float* Ag = V + NB * NS * ND;              // gamma * Q_trans, [46,50,50]

    qkv_gemm<<<dim3(36, 12, 3), 256, 0, stream>>>(text_emb, emb, Wq, bq, Wk, bk, Wv, bv, Q, K, V);
    attn<<<dim3(NM), 64, 0, stream>>>(Q, K, V, lw, lb, Ag, ctx);
    recur<<<dim3(552), 256, 0, stream>>>(Ag, ctx, rec);
}

// Round 8
// 423.294 us; speedup vs baseline: 2.4691x; 1.1681x over previous
//
#include <hip/hip_runtime.h>
#include <math.h>

#define NB 46
#define NS 50
#define ND 768
#define GAMA 0.96875f
#define NM 2300   // NB*NS rows

typedef float v2f __attribute__((ext_vector_type(2)));
using bfrag  = __attribute__((ext_vector_type(8))) short;   // 8 bf16 = 4 VGPRs
using f32x16 = __attribute__((ext_vector_type(16))) float;  // 32x32 acc

union FragU { unsigned u[4]; bfrag f; };

// ---------------- Kernel 1: QKV projections (+bias, +pe for Q,K) ----------
__global__ __launch_bounds__(256) void qkv_gemm(
    const float* __restrict__ text_emb, const float* __restrict__ emb,
    const float* __restrict__ Wq, const float* __restrict__ bq,
    const float* __restrict__ Wk, const float* __restrict__ bk,
    const float* __restrict__ Wv, const float* __restrict__ bv,
    float* __restrict__ Q, float* __restrict__ K, float* __restrict__ V)
{
    const int z = blockIdx.z;
    const float* X    = (z == 0) ? text_emb : emb;
    const float* W    = (z == 0) ? Wq : (z == 1) ? Wk : Wv;
    const float* bias = (z == 0) ? bq : (z == 1) ? bk : bv;
    float* out        = (z == 0) ? Q  : (z == 1) ? K  : V;

    __shared__ float Xs[16][68];
    __shared__ float Ws[16][68];

    const int tid = threadIdx.x;
    const int tx = tid & 15, ty = tid >> 4;
    const int m0 = blockIdx.x * 64, n0 = blockIdx.y * 64;

    const int lrow = tid >> 2;        // 0..63
    const int lk   = (tid & 3) * 4;   // 0,4,8,12

    float acc[4][4];
    #pragma unroll
    for (int i = 0; i < 4; i++)
        #pragma unroll
        for (int j = 0; j < 4; j++) acc[i][j] = 0.f;

    for (int k0 = 0; k0 < ND; k0 += 16) {
        float4 xv = make_float4(0.f, 0.f, 0.f, 0.f);
        const int xm = m0 + lrow;
        if (xm < NM) xv = *reinterpret_cast<const float4*>(&X[xm * ND + k0 + lk]);
        const float4 wv = *reinterpret_cast<const float4*>(&W[(n0 + lrow) * ND + k0 + lk]);
        Xs[lk + 0][lrow] = xv.x; Xs[lk + 1][lrow] = xv.y;
        Xs[lk + 2][lrow] = xv.z; Xs[lk + 3][lrow] = xv.w;
        Ws[lk + 0][lrow] = wv.x; Ws[lk + 1][lrow] = wv.y;
        Ws[lk + 2][lrow] = wv.z; Ws[lk + 3][lrow] = wv.w;
        __syncthreads();
        #pragma unroll
        for (int k = 0; k < 16; k++) {
            const float4 a  = *reinterpret_cast<const float4*>(&Xs[k][4 * ty]);
            const float4 b4 = *reinterpret_cast<const float4*>(&Ws[k][4 * tx]);
            const float av[4]  = {a.x,  a.y,  a.z,  a.w};
            const float bv4[4] = {b4.x, b4.y, b4.z, b4.w};
            #pragma unroll
            for (int i = 0; i < 4; i++)
                #pragma unroll
                for (int j = 0; j < 4; j++) acc[i][j] += av[i] * bv4[j];
        }
        __syncthreads();
    }

    const float C2 = -0.0239861701969175f; // -2*ln(10000)/768
    #pragma unroll
    for (int i = 0; i < 4; i++) {
        const int m = m0 + 4 * ty + i;
        if (m >= NM) continue;
        const int bpos = m / NS;  // pe indexed by BATCH position (faithful to source)
        #pragma unroll
        for (int j = 0; j < 4; j++) {
            const int n = n0 + 4 * tx + j;
            float v = acc[i][j] + bias[n];
            if (z < 2) {
                const int h = n >> 1;
                const float ang = (float)bpos * expf((float)h * C2);
                v += (n & 1) ? cosf(ang) : sinf(ang);
            }
            out[m * ND + n] = v;
        }
    }
}

// ---------------- Kernel 2: scores+softmax+ctx, and Ag = gamma*Q_trans -----
__global__ __launch_bounds__(64) void attn(
    const float* __restrict__ Q, const float* __restrict__ K,
    const float* __restrict__ V,
    const float* __restrict__ lin_w, const float* __restrict__ lin_b,
    float* __restrict__ Ag, float* __restrict__ ctx_out)
{
    const int bq = blockIdx.x;
    const int b = bq / NS, q = bq % NS;
    const int lane = threadIdx.x;

    const float* Qr = Q + (b * NS + q) * ND;
    float qv[12];
    #pragma unroll
    for (int m = 0; m < 12; m++) qv[m] = Qr[m * 64 + lane];

    // scores: lane k ends up holding score[k]*8
    float mysc = 0.f;
    for (int k = 0; k < NS; k++) {
        const float* Kr = K + (b * NS + k) * ND;
        float s = 0.f;
        #pragma unroll
        for (int m = 0; m < 12; m++) s += qv[m] * Kr[m * 64 + lane];
        #pragma unroll
        for (int off = 32; off; off >>= 1) s += __shfl_xor(s, off);
        if (lane == k) mysc = s * 8.f;
    }
    // Q_trans row q: lane j holds Qt[j]; write Ag = gamma*(Qt + lin_b)
    float myqt = 0.f;
    for (int j = 0; j < NS; j++) {
        const float* Lr = lin_w + j * ND;
        float s = 0.f;
        #pragma unroll
        for (int m = 0; m < 12; m++) s += qv[m] * Lr[m * 64 + lane];
        #pragma unroll
        for (int off = 32; off; off >>= 1) s += __shfl_xor(s, off);
        if (lane == j) myqt = s;
    }
    if (lane < NS)
        Ag[b * (NS * NS) + q * NS + lane] = GAMA * (myqt + lin_b[lane]);

    // softmax over lanes 0..49
    const float sc = (lane < NS) ? mysc : -INFINITY;
    float mx = sc;
    #pragma unroll
    for (int off = 32; off; off >>= 1) mx = fmaxf(mx, __shfl_xor(mx, off));
    const float e = (lane < NS) ? expf(sc - mx) : 0.f;
    float sum = e;
    #pragma unroll
    for (int off = 32; off; off >>= 1) sum += __shfl_xor(sum, off);
    const float p = e / sum;

    // ctx row = sum_k p_k * V[b,k,:]
    float acc[12];
    #pragma unroll
    for (int m = 0; m < 12; m++) acc[m] = 0.f;
    for (int k = 0; k < NS; k++) {
        const float pk = __shfl(p, k);
        const float* Vr = V + (b * NS + k) * ND;
        #pragma unroll
        for (int m = 0; m < 12; m++) acc[m] += pk * Vr[m * 64 + lane];
    }
    float* Cr = ctx_out + (b * NS + q) * ND;
    #pragma unroll
    for (int m = 0; m < 12; m++) Cr[m * 64 + lane] = acc[m];
}

// ---------------- Kernel 3: gamma-decay recurrence via MFMA ----------------
// rec[i,b,:,:] = Ag_b @ rec[i-1,b,:,:] + ctx[i], [50x50]@[50x64] padded to 64.
// R7 lesson: LDS-broadcast A reads are BW-bound (64 lanes x same 16B); A is
// step-invariant -> hold A in MFMA fragments (VGPRs), per-step A traffic = 0.
// One wave per (b, 64-col chunk); no barriers (DS in-order within a wave).
// Precision: trunc hi/lo bf16 split of A (once) and state (per step):
//   A@s ~= Ah@sh + Ah@sl + Al@sh   (err ~5e-5/step, 45 steps -> ~2e-3 rel)
// State carried as packed u32(hi16,lo16) in LDS P[k=64][n=64]; C/D layout
// (col=lane&31,row=(reg&3)+8(reg>>2)+4(lane>>5)) -> write P; B-frag layout
// (n=lane&31, k=(lane>>5)*8+j) -> read P. nt=0/1 column halves are disjoint,
// so read-then-write per half needs no sync. ctx loads open each step so
// their vmcnt wait sits ahead of this step's NT stores (R6 FIFO lesson).
__global__ __launch_bounds__(64, 1) void recur(
    const float* __restrict__ Ag, const float* __restrict__ ctx,
    float* __restrict__ rec)
{
    const int blk   = blockIdx.x;
    const int b     = blk / 12;
    const int chunk = blk - b * 12;
    const int l     = threadIdx.x;
    const int c     = l & 31;          // col within 32-tile
    const int h     = l >> 5;          // lane half
    const int d0    = chunk * 64;

    __shared__ float    Af[64 * 64];   // A padded, 16 KB (prologue only)
    __shared__ unsigned P [64 * 64];   // state packed (hi16|lo16), 16 KB

    // ---- stage A padded to 64x64 (zeros beyond 50x50) ----
    const float* __restrict__ Ab = Ag + b * (NS * NS);
    for (int idx = l; idx < 64 * 64; idx += 64) {
        const int r = idx >> 6, j = idx & 63;
        Af[idx] = (r < NS && j < NS) ? Ab[r * NS + j] : 0.f;
    }

    // ---- A fragments (hi/lo), loaded ONCE: lane holds row=32mt+c, k=16kt+8h+j
    bfrag Ah[2][4], Al[2][4];
    #pragma unroll
    for (int mt = 0; mt < 2; mt++) {
        #pragma unroll
        for (int kt = 0; kt < 4; kt++) {
            const int base = (32 * mt + c) * 64 + 16 * kt + 8 * h;
            FragU uh, ul;
            #pragma unroll
            for (int t = 0; t < 4; t++) {
                const float e = Af[base + 2 * t];
                const float o = Af[base + 2 * t + 1];
                const unsigned ue = __float_as_uint(e), uo = __float_as_uint(o);
                uh.u[t] = (ue >> 16) | (uo & 0xFFFF0000u);
                const float re = e - __uint_as_float(ue & 0xFFFF0000u);
                const float ro = o - __uint_as_float(uo & 0xFFFF0000u);
                ul.u[t] = (__float_as_uint(re) >> 16) | (__float_as_uint(ro) & 0xFFFF0000u);
            }
            Ah[mt][kt] = uh.f; Al[mt][kt] = ul.f;
        }
    }

    // ---- step 0: s_0 = ctx[0]; write rec[0] and P ----
    {
        const float* __restrict__ c0  = ctx + d0;
        float* __restrict__       rp0 = rec + (size_t)b * NS * ND + d0;
        for (int r = 0; r < NS; r++) {
            const float v = c0[r * ND + l];
            __builtin_nontemporal_store(v, &rp0[r * ND + l]);
            const unsigned hi = __float_as_uint(v) & 0xFFFF0000u;
            const float res = v - __uint_as_float(hi);
            P[r * 64 + l] = hi | (__float_as_uint(res) >> 16);
        }
        #pragma unroll
        for (int r = NS; r < 64; r++) P[r * 64 + l] = 0u;
    }

    // ---- steps 1..45 ----
    for (int i = 1; i < NB; ++i) {
        const float* __restrict__ ctxi = ctx + (size_t)i * NS * ND + d0;
        float* __restrict__       reci = rec + (size_t)(i * NB + b) * NS * ND + d0;

        // acc := ctx_i (0 in pad rows) — issued first (ahead of this step's stores)
        f32x16 acc[2][2];
        #pragma unroll
        for (int mt = 0; mt < 2; mt++)
            #pragma unroll
            for (int nt = 0; nt < 2; nt++)
                #pragma unroll
                for (int g = 0; g < 16; g++) {
                    const int rg = 32 * mt + (g & 3) + 8 * (g >> 2) + 4 * h;
                    float v = 0.f;
                    if (rg < NS) v = ctxi[rg * ND + 32 * nt + c];
                    acc[mt][nt][g] = v;
                }

        #pragma unroll
        for (int nt = 0; nt < 2; nt++) {
            // B-frags of s_{i-1} from P (cols 32nt+c only)
            bfrag Bh[4], Bl[4];
            #pragma unroll
            for (int kt = 0; kt < 4; kt++) {
                unsigned pw[8];
                #pragma unroll
                for (int j = 0; j < 8; j++)
                    pw[j] = P[(16 * kt + 8 * h + j) * 64 + 32 * nt + c];
                FragU uh, ul;
                #pragma unroll
                for (int t = 0; t < 4; t++) {
                    uh.u[t] = (pw[2 * t] >> 16)      | (pw[2 * t + 1] & 0xFFFF0000u);
                    ul.u[t] = (pw[2 * t] & 0xFFFFu)  | (pw[2 * t + 1] << 16);
                }
                Bh[kt] = uh.f; Bl[kt] = ul.f;
            }

            // 24 MFMA per nt-half: hi*hi, hi*lo, lo*hi
            #pragma unroll
            for (int mt = 0; mt < 2; mt++) {
                f32x16 a = acc[mt][nt];
                #pragma unroll
                for (int kt = 0; kt < 4; kt++)
                    a = __builtin_amdgcn_mfma_f32_32x32x16_bf16(Ah[mt][kt], Bh[kt], a, 0, 0, 0);
                #pragma unroll
                for (int kt = 0; kt < 4; kt++)
                    a = __builtin_amdgcn_mfma_f32_32x32x16_bf16(Ah[mt][kt], Bl[kt], a, 0, 0, 0);
                #pragma unroll
                for (int kt = 0; kt < 4; kt++)
                    a = __builtin_amdgcn_mfma_f32_32x32x16_bf16(Al[mt][kt], Bh[kt], a, 0, 0, 0);
                acc[mt][nt] = a;
            }

            // store rec + repack state into P (same disjoint cols; after reads)
            #pragma unroll
            for (int mt = 0; mt < 2; mt++)
                #pragma unroll
                for (int g = 0; g < 16; g++) {
                    const int rg = 32 * mt + (g & 3) + 8 * (g >> 2) + 4 * h;
                    const float v = acc[mt][nt][g];
                    const unsigned hi = __float_as_uint(v) & 0xFFFF0000u;
                    const float res = v - __uint_as_float(hi);
                    P[rg * 64 + 32 * nt + c] = hi | (__float_as_uint(res) >> 16);
                    if (rg < NS)
                        __builtin_nontemporal_store(v, &reci[rg * ND + 32 * nt + c]);
                }
        }
    }
}

extern "C" void kernel_launch(void* const* d_in, const int* in_sizes, int n_in,
                              void* d_out, int out_size, void* d_ws, size_t ws_size,
                              hipStream_t stream) {
    const float* text_emb = (const float*)d_in[0];
    const float* emb      = (const float*)d_in[1];
    const float* Wq = (const float*)d_in[2]; const float* bq = (const float*)d_in[3];
    const float* Wk = (const float*)d_in[4]; const float* bk = (const float*)d_in[5];
    const float* Wv = (const float*)d_in[6]; const float* bv = (const float*)d_in[7];
    const float* lw = (const float*)d_in[8]; const float* lb = (const float*)d_in[9];

    float* out = (float*)d_out;
    float* ctx = out;                          // [46,50,768]
    float* rec = out + NB * NS * ND;           // [46,46,50,768]

    float* ws = (float*)d_ws;                  // needs 21.7 MB
    float* Q  = ws;
    float* K  = Q + NB * NS * ND;
    float* V  = K + NB * NS * ND;
    float* Ag = V + NB * NS * ND;              // gamma * Q_trans, [46,50,50]

    qkv_gemm<<<dim3(36, 12, 3), 256, 0, stream>>>(text_emb, emb, Wq, bq, Wk, bk, Wv, bv, Q, K, V);
    attn<<<dim3(NM), 64, 0, stream>>>(Q, K, V, lw, lb, Ag, ctx);
    recur<<<dim3(552), 64, 0, stream>>>(Ag, ctx, rec);
}

// Round 9
// 401.731 us; speedup vs baseline: 2.6016x; 1.0537x over previous
//
#include <hip/hip_runtime.h>
#include <math.h>

#define NB 46
#define NS 50
#define ND 768
#define GAMA 0.96875f
#define NM 2300   // NB*NS rows

using bfrag  = __attribute__((ext_vector_type(8))) short;   // 8 bf16 = 4 VGPRs
using f32x16 = __attribute__((ext_vector_type(16))) float;  // 32x32 acc

union FragU { unsigned u[4]; bfrag f; };

// ---------------- Kernel 1: QKV projections (+bias, +pe for Q,K) ----------
__global__ __launch_bounds__(256) void qkv_gemm(
    const float* __restrict__ text_emb, const float* __restrict__ emb,
    const float* __restrict__ Wq, const float* __restrict__ bq,
    const float* __restrict__ Wk, const float* __restrict__ bk,
    const float* __restrict__ Wv, const float* __restrict__ bv,
    float* __restrict__ Q, float* __restrict__ K, float* __restrict__ V)
{
    const int z = blockIdx.z;
    const float* X    = (z == 0) ? text_emb : emb;
    const float* W    = (z == 0) ? Wq : (z == 1) ? Wk : Wv;
    const float* bias = (z == 0) ? bq : (z == 1) ? bk : bv;
    float* out        = (z == 0) ? Q  : (z == 1) ? K  : V;

    __shared__ float Xs[16][68];
    __shared__ float Ws[16][68];

    const int tid = threadIdx.x;
    const int tx = tid & 15, ty = tid >> 4;
    const int m0 = blockIdx.x * 64, n0 = blockIdx.y * 64;

    const int lrow = tid >> 2;        // 0..63
    const int lk   = (tid & 3) * 4;   // 0,4,8,12

    float acc[4][4];
    #pragma unroll
    for (int i = 0; i < 4; i++)
        #pragma unroll
        for (int j = 0; j < 4; j++) acc[i][j] = 0.f;

    for (int k0 = 0; k0 < ND; k0 += 16) {
        float4 xv = make_float4(0.f, 0.f, 0.f, 0.f);
        const int xm = m0 + lrow;
        if (xm < NM) xv = *reinterpret_cast<const float4*>(&X[xm * ND + k0 + lk]);
        const float4 wv = *reinterpret_cast<const float4*>(&W[(n0 + lrow) * ND + k0 + lk]);
        Xs[lk + 0][lrow] = xv.x; Xs[lk + 1][lrow] = xv.y;
        Xs[lk + 2][lrow] = xv.z; Xs[lk + 3][lrow] = xv.w;
        Ws[lk + 0][lrow] = wv.x; Ws[lk + 1][lrow] = wv.y;
        Ws[lk + 2][lrow] = wv.z; Ws[lk + 3][lrow] = wv.w;
        __syncthreads();
        #pragma unroll
        for (int k = 0; k < 16; k++) {
            const float4 a  = *reinterpret_cast<const float4*>(&Xs[k][4 * ty]);
            const float4 b4 = *reinterpret_cast<const float4*>(&Ws[k][4 * tx]);
            const float av[4]  = {a.x,  a.y,  a.z,  a.w};
            const float bv4[4] = {b4.x, b4.y, b4.z, b4.w};
            #pragma unroll
            for (int i = 0; i < 4; i++)
                #pragma unroll
                for (int j = 0; j < 4; j++) acc[i][j] += av[i] * bv4[j];
        }
        __syncthreads();
    }

    const float C2 = -0.0239861701969175f; // -2*ln(10000)/768
    #pragma unroll
    for (int i = 0; i < 4; i++) {
        const int m = m0 + 4 * ty + i;
        if (m >= NM) continue;
        const int bpos = m / NS;  // pe indexed by BATCH position (faithful to source)
        #pragma unroll
        for (int j = 0; j < 4; j++) {
            const int n = n0 + 4 * tx + j;
            float v = acc[i][j] + bias[n];
            if (z < 2) {
                const int h = n >> 1;
                const float ang = (float)bpos * expf((float)h * C2);
                v += (n & 1) ? cosf(ang) : sinf(ang);
            }
            out[m * ND + n] = v;
        }
    }
}

// ---------------- Kernel 2: scores+softmax+ctx, and Ag = gamma*Q_trans -----
__global__ __launch_bounds__(64) void attn(
    const float* __restrict__ Q, const float* __restrict__ K,
    const float* __restrict__ V,
    const float* __restrict__ lin_w, const float* __restrict__ lin_b,
    float* __restrict__ Ag, float* __restrict__ ctx_out)
{
    const int bq = blockIdx.x;
    const int b = bq / NS, q = bq % NS;
    const int lane = threadIdx.x;

    const float* Qr = Q + (b * NS + q) * ND;
    float qv[12];
    #pragma unroll
    for (int m = 0; m < 12; m++) qv[m] = Qr[m * 64 + lane];

    // scores: lane k ends up holding score[k]*8
    float mysc = 0.f;
    for (int k = 0; k < NS; k++) {
        const float* Kr = K + (b * NS + k) * ND;
        float s = 0.f;
        #pragma unroll
        for (int m = 0; m < 12; m++) s += qv[m] * Kr[m * 64 + lane];
        #pragma unroll
        for (int off = 32; off; off >>= 1) s += __shfl_xor(s, off);
        if (lane == k) mysc = s * 8.f;
    }
    // Q_trans row q: lane j holds Qt[j]; write Ag = gamma*(Qt + lin_b)
    float myqt = 0.f;
    for (int j = 0; j < NS; j++) {
        const float* Lr = lin_w + j * ND;
        float s = 0.f;
        #pragma unroll
        for (int m = 0; m < 12; m++) s += qv[m] * Lr[m * 64 + lane];
        #pragma unroll
        for (int off = 32; off; off >>= 1) s += __shfl_xor(s, off);
        if (lane == j) myqt = s;
    }
    if (lane < NS)
        Ag[b * (NS * NS) + q * NS + lane] = GAMA * (myqt + lin_b[lane]);

    // softmax over lanes 0..49
    const float sc = (lane < NS) ? mysc : -INFINITY;
    float mx = sc;
    #pragma unroll
    for (int off = 32; off; off >>= 1) mx = fmaxf(mx, __shfl_xor(mx, off));
    const float e = (lane < NS) ? expf(sc - mx) : 0.f;
    float sum = e;
    #pragma unroll
    for (int off = 32; off; off >>= 1) sum += __shfl_xor(sum, off);
    const float p = e / sum;

    // ctx row = sum_k p_k * V[b,k,:]
    float acc[12];
    #pragma unroll
    for (int m = 0; m < 12; m++) acc[m] = 0.f;
    for (int k = 0; k < NS; k++) {
        const float pk = __shfl(p, k);
        const float* Vr = V + (b * NS + k) * ND;
        #pragma unroll
        for (int m = 0; m < 12; m++) acc[m] += pk * Vr[m * 64 + lane];
    }
    float* Cr = ctx_out + (b * NS + q) * ND;
    #pragma unroll
    for (int m = 0; m < 12; m++) Cr[m * 64 + lane] = acc[m];
}

// ---------------- Kernel 3: gamma-decay recurrence via MFMA ----------------
// rec[i,b,:,:] = Ag_b @ rec[i-1,b,:,:] + ctx[i], padded 50->64 on M,K.
// One wave per (b, 32-col chunk): 1104 blocks (~4.3/CU). A held in bf16
// hi/lo MFMA fragments loaded ONCE directly from global (no LDS staging ->
// no 32-way broadcast conflicts). State packed (hi16|lo16) in LDS P[64][32]
// (bank = col, conflict-free), read as B-frags, rewritten after MFMA (DS is
// in-order within a wave, no barriers). R8 lesson: ctx for step i+1 is
// prefetched into a ping-pong register buffer BEFORE step i's NT stores, so
// the acc-init wait is vmcnt(<=25) and never drains young stores (R6 FIFO).
__device__ __forceinline__ void rec_step(
    int i, int b, int d0, int c, int h, bool pf,
    const bfrag (&Ah)[2][4], const bfrag (&Al)[2][4],
    float (&cur)[2][16], float (&nxt)[2][16],
    unsigned* P, const float* __restrict__ ctx, float* __restrict__ rec)
{
    // acc := ctx_i (pad rows already 0 in cur)
    f32x16 acc[2];
    #pragma unroll
    for (int mt = 0; mt < 2; mt++)
        #pragma unroll
        for (int g = 0; g < 16; g++)
            acc[mt][g] = cur[mt][g];

    // prefetch ctx_{i+1} BEFORE this step's stores (FIFO discipline)
    if (pf) {
        const float* __restrict__ ctxn = ctx + (size_t)(i + 1) * NS * ND + d0 + c;
        #pragma unroll
        for (int mt = 0; mt < 2; mt++)
            #pragma unroll
            for (int g = 0; g < 16; g++) {
                const int rg = 32 * mt + (g & 3) + 8 * (g >> 2) + 4 * h;
                nxt[mt][g] = (rg < NS) ? ctxn[(size_t)rg * ND] : 0.f;
            }
    }

    // B-frags of s_{i-1} from P
    bfrag Bh[4], Bl[4];
    #pragma unroll
    for (int kt = 0; kt < 4; kt++) {
        unsigned pw[8];
        #pragma unroll
        for (int j = 0; j < 8; j++)
            pw[j] = P[(16 * kt + 8 * h + j) * 32 + c];
        FragU uh, ul;
        #pragma unroll
        for (int t = 0; t < 4; t++) {
            uh.u[t] = (pw[2 * t] >> 16)     | (pw[2 * t + 1] & 0xFFFF0000u);
            ul.u[t] = (pw[2 * t] & 0xFFFFu) | (pw[2 * t + 1] << 16);
        }
        Bh[kt] = uh.f; Bl[kt] = ul.f;
    }

    // 12 MFMA per mt: hi*hi, hi*lo, lo*hi
    #pragma unroll
    for (int mt = 0; mt < 2; mt++) {
        f32x16 a = acc[mt];
        #pragma unroll
        for (int kt = 0; kt < 4; kt++)
            a = __builtin_amdgcn_mfma_f32_32x32x16_bf16(Ah[mt][kt], Bh[kt], a, 0, 0, 0);
        #pragma unroll
        for (int kt = 0; kt < 4; kt++)
            a = __builtin_amdgcn_mfma_f32_32x32x16_bf16(Ah[mt][kt], Bl[kt], a, 0, 0, 0);
        #pragma unroll
        for (int kt = 0; kt < 4; kt++)
            a = __builtin_amdgcn_mfma_f32_32x32x16_bf16(Al[mt][kt], Bh[kt], a, 0, 0, 0);
        acc[mt] = a;
    }

    // repack state into P (pad rows produce exact 0) + NT store rec
    float* __restrict__ reci = rec + (size_t)(i * NB + b) * NS * ND + d0 + c;
    #pragma unroll
    for (int mt = 0; mt < 2; mt++)
        #pragma unroll
        for (int g = 0; g < 16; g++) {
            const int rg = 32 * mt + (g & 3) + 8 * (g >> 2) + 4 * h;
            const float v = acc[mt][g];
            const unsigned hi = __float_as_uint(v) & 0xFFFF0000u;
            const float res = v - __uint_as_float(hi);
            P[rg * 32 + c] = hi | (__float_as_uint(res) >> 16);
            if (rg < NS)
                __builtin_nontemporal_store(v, &reci[(size_t)rg * ND]);
        }
}

__global__ __launch_bounds__(64, 1) void recur(
    const float* __restrict__ Ag, const float* __restrict__ ctx,
    float* __restrict__ rec)
{
    const int blk   = blockIdx.x;          // 0..1103
    const int b     = blk / 24;
    const int chunk = blk - b * 24;        // 0..23 -> 32 cols
    const int l     = threadIdx.x;
    const int c     = l & 31;
    const int h     = l >> 5;
    const int d0    = chunk * 32;

    __shared__ unsigned P[64 * 32];        // packed state (hi16|lo16), 8 KB

    // ---- A fragments (hi/lo), ONCE, straight from global (L2-resident) ----
    const float* __restrict__ Ab = Ag + b * (NS * NS);
    bfrag Ah[2][4], Al[2][4];
    #pragma unroll
    for (int mt = 0; mt < 2; mt++) {
        const int row = 32 * mt + c;
        const bool rok = row < NS;
        const float* __restrict__ Arow = Ab + row * NS;
        #pragma unroll
        for (int kt = 0; kt < 4; kt++) {
            FragU uh, ul;
            #pragma unroll
            for (int t = 0; t < 4; t++) {
                const int k0 = 16 * kt + 8 * h + 2 * t;
                const float e = (rok && k0     < NS) ? Arow[k0]     : 0.f;
                const float o = (rok && k0 + 1 < NS) ? Arow[k0 + 1] : 0.f;
                const unsigned ue = __float_as_uint(e), uo = __float_as_uint(o);
                uh.u[t] = (ue >> 16) | (uo & 0xFFFF0000u);
                const float re = e - __uint_as_float(ue & 0xFFFF0000u);
                const float ro = o - __uint_as_float(uo & 0xFFFF0000u);
                ul.u[t] = (__float_as_uint(re) >> 16) | (__float_as_uint(ro) & 0xFFFF0000u);
            }
            Ah[mt][kt] = uh.f; Al[mt][kt] = ul.f;
        }
    }

    // ---- step 0: cvA = ctx[0]; prefetch ctx[1] -> cvB; then pack/store ----
    float cvA[2][16], cvB[2][16];
    {
        const float* __restrict__ c0 = ctx + d0 + c;
        #pragma unroll
        for (int mt = 0; mt < 2; mt++)
            #pragma unroll
            for (int g = 0; g < 16; g++) {
                const int rg = 32 * mt + (g & 3) + 8 * (g >> 2) + 4 * h;
                cvA[mt][g] = (rg < NS) ? c0[(size_t)rg * ND] : 0.f;
            }
        const float* __restrict__ c1 = ctx + NS * ND + d0 + c;
        #pragma unroll
        for (int mt = 0; mt < 2; mt++)
            #pragma unroll
            for (int g = 0; g < 16; g++) {
                const int rg = 32 * mt + (g & 3) + 8 * (g >> 2) + 4 * h;
                cvB[mt][g] = (rg < NS) ? c1[(size_t)rg * ND] : 0.f;
            }
        float* __restrict__ r0 = rec + (size_t)b * NS * ND + d0 + c;
        #pragma unroll
        for (int mt = 0; mt < 2; mt++)
            #pragma unroll
            for (int g = 0; g < 16; g++) {
                const int rg = 32 * mt + (g & 3) + 8 * (g >> 2) + 4 * h;
                const float v = cvA[mt][g];
                const unsigned hi = __float_as_uint(v) & 0xFFFF0000u;
                const float res = v - __uint_as_float(hi);
                P[rg * 32 + c] = hi | (__float_as_uint(res) >> 16);
                if (rg < NS)
                    __builtin_nontemporal_store(v, &r0[(size_t)rg * ND]);
            }
    }

    // ---- steps 1..45, 2x unrolled ping-pong (static indices, rule #20) ----
    for (int i = 1; i < NB; i += 2) {
        rec_step(i, b, d0, c, h, (i + 1 < NB), Ah, Al, cvB, cvA, P, ctx, rec);
        if (i + 1 < NB)
            rec_step(i + 1, b, d0, c, h, (i + 2 < NB), Ah, Al, cvA, cvB, P, ctx, rec);
    }
}

extern "C" void kernel_launch(void* const* d_in, const int* in_sizes, int n_in,
                              void* d_out, int out_size, void* d_ws, size_t ws_size,
                              hipStream_t stream) {
    const float* text_emb = (const float*)d_in[0];
    const float* emb      = (const float*)d_in[1];
    const float* Wq = (const float*)d_in[2]; const float* bq = (const float*)d_in[3];
    const float* Wk = (const float*)d_in[4]; const float* bk = (const float*)d_in[5];
    const float* Wv = (const float*)d_in[6]; const float* bv = (const float*)d_in[7];
    const float* lw = (const float*)d_in[8]; const float* lb = (const float*)d_in[9];

    float* out = (float*)d_out;
    float* ctx = out;                          // [46,50,768]
    float* rec = out + NB * NS * ND;           // [46,46,50,768]

    float* ws = (float*)d_ws;                  // needs 21.7 MB
    float* Q  = ws;
    float* K  = Q + NB * NS * ND;
    float* V  = K + NB * NS * ND;
    float* Ag = V + NB * NS * ND;              // gamma * Q_trans, [46,50,50]

    qkv_gemm<<<dim3(36, 12, 3), 256, 0, stream>>>(text_emb, emb, Wq, bq, Wk, bk, Wv, bv, Q, K, V);
    attn<<<dim3(NM), 64, 0, stream>>>(Q, K, V, lw, lb, Ag, ctx);
    recur<<<dim3(1104), 64, 0, stream>>>(Ag, ctx, rec);
}